// Round 10
// baseline (199.350 us; speedup 1.0000x reference)
//
#include <hip/hip_runtime.h>
#include <hip/hip_bf16.h>

typedef __attribute__((ext_vector_type(8))) short short8;
typedef __attribute__((ext_vector_type(4))) float f32x4;

static inline int cdiv(int a, int b) { return (a + b - 1) / b; }

__device__ inline float bf2f(unsigned short u) {
    union { unsigned int u; float f; } a; a.u = ((unsigned int)u) << 16; return a.f;
}
__device__ inline unsigned short f2bf(float f) {
    union { float f; unsigned int u; } a; a.f = f;
    unsigned int r = a.u + 0x7fff + ((a.u >> 16) & 1);
    return (unsigned short)(r >> 16);
}
__device__ inline void gload_lds16(const void* g, void* l) {
    __builtin_amdgcn_global_load_lds(
        (const __attribute__((address_space(1))) unsigned int*)g,
        (__attribute__((address_space(3))) unsigned int*)l, 16, 0, 0);
}

// ---------------- preprocessing ----------------
// XCD-replicated counting: rep = blockIdx&7 (matches round-robin block->XCD).
// Each rep's counter lines are touched by one XCD only -> no cross-XCD
// line ping-pong through HBM (r9 evidence: WRITE_SIZE 25MB for 800KB counters).
__global__ __launch_bounds__(256) void count_both_k(
    const int* __restrict__ rows, const int* __restrict__ cols,
    float* deg8, int* indeg8, int E, int N)
{
    int rep = blockIdx.x & 7;
    int e = blockIdx.x * 256 + threadIdx.x;
    if (e < E) {
        atomicAdd(&deg8[rep * N + rows[e]], 1.0f);
        atomicAdd(&indeg8[rep * N + cols[e]], 1);
    }
}

// block b handles 128 nodes x 8 reps = 1024 elements in (node, rep) order.
// writes local-scan cursor values + local rowstart + block total.
__global__ __launch_bounds__(256) void scan_block_k(
    const int* __restrict__ indeg8, int* __restrict__ rowstart,
    int* __restrict__ cursor8, int* __restrict__ bsums, int N)
{
    __shared__ int smem[256];
    int b = blockIdx.x, t = threadIdx.x;
    int node = b * 128 + (t >> 1);
    int half = t & 1;                      // reps half*4 .. half*4+3
    int v[4];
    int s = 0;
    #pragma unroll
    for (int j = 0; j < 4; ++j) {
        int rep = half * 4 + j;
        v[j] = (node < N) ? indeg8[rep * N + node] : 0;
        s += v[j];
    }
    smem[t] = s;
    __syncthreads();
    for (int off = 1; off < 256; off <<= 1) {
        int x = smem[t];
        int y = (t >= off) ? smem[t - off] : 0;
        __syncthreads();
        smem[t] = x + y;
        __syncthreads();
    }
    int excl = smem[t] - s;
    if (node < N) {
        int p = excl;
        #pragma unroll
        for (int j = 0; j < 4; ++j) {
            int rep = half * 4 + j;
            cursor8[rep * N + node] = p;
            p += v[j];
        }
        if (half == 0) rowstart[node] = excl;
    }
    if (t == 255) bsums[b] = smem[255];
}

// re-scans <=512 block sums locally; applies offsets to rowstart + cursor8;
// computes dinv = rsqrt(1 + sum_rep deg8).
__global__ __launch_bounds__(256) void scan_add_dinv_k(
    int* rowstart, int* cursor8, const int* __restrict__ bsums, int nbk,
    const float* __restrict__ deg8, float* __restrict__ dinv, int N, int E)
{
    __shared__ int sb[512];
    int t = threadIdx.x;
    sb[t]       = (t < nbk) ? bsums[t] : 0;
    sb[t + 256] = (t + 256 < nbk) ? bsums[t + 256] : 0;
    __syncthreads();
    for (int off = 1; off < 512; off <<= 1) {
        int x0 = sb[t]       + ((t >= off) ? sb[t - off] : 0);
        int x1 = sb[t + 256] + ((t + 256 >= off) ? sb[t + 256 - off] : 0);
        __syncthreads();
        sb[t] = x0; sb[t + 256] = x1;
        __syncthreads();
    }
    int i = blockIdx.x * 256 + t;
    if (i < N) {
        int blk = i >> 7;                  // 128 nodes per scan block
        int off = (blk == 0) ? 0 : sb[blk - 1];
        rowstart[i] += off;
        float d = 1.0f;
        #pragma unroll
        for (int rep = 0; rep < 8; ++rep) {
            cursor8[rep * N + i] += off;
            d += deg8[rep * N + i];
        }
        dinv[i] = rsqrtf(d);
    }
    if (blockIdx.x == 0 && t == 0) rowstart[N] = E;
}

__global__ __launch_bounds__(256) void fill_csr_k(
    const int* __restrict__ rows, const int* __restrict__ cols,
    int* cursor8, int* __restrict__ csr, int E, int N)
{
    int rep = blockIdx.x & 7;              // same mapping as count_both_k
    int e = blockIdx.x * 256 + threadIdx.x;
    if (e < E) {
        int pos = atomicAdd(&cursor8[rep * N + cols[e]], 1);
        csr[pos] = rows[e];
    }
}

// weight transposes (to bf16 Wt[m][k]) + zero of replicated counters
__global__ __launch_bounds__(256) void prep_weights_zero_k(
    const float* __restrict__ W1, const float* __restrict__ W2, const float* __restrict__ Wh,
    unsigned short* __restrict__ Wt1, unsigned short* __restrict__ Wt2, unsigned short* __restrict__ Wht,
    float4* __restrict__ zp, int nz4)
{
    int idx = blockIdx.x * 256 + threadIdx.x;
    if (idx < nz4) zp[idx] = make_float4(0.f, 0.f, 0.f, 0.f);
    if (idx < 65536) {
        int k = idx >> 8, m = idx & 255;
        Wt1[m * 256 + k] = f2bf(W1[idx]);
    } else if (idx < 131072) {
        int i = idx - 65536;
        int k = i >> 8, m = i & 255;
        Wt2[m * 256 + k] = f2bf(W2[i]);
    } else if (idx < 147456) {
        int i = idx - 131072;
        int k = i >> 6, m = i & 63;    // Wh is 256 x 64
        Wht[m * 256 + k] = f2bf(Wh[i]);
    }
}

// ---------------- MFMA GEMM, 2-phase double-buffered ----------------
// ASRC 0: A bf16 via global_load_lds; ASRC 1: A fp32 via reg-stage + cvt (T14).
// NYB 2: XCD-paired decode (both col-halves of an M-tile on one XCD -> A L2 reuse).
template<int BN, int MODE, int ASRC, int NYB>
__global__ __launch_bounds__(256) void gemm_mfma_k(
    const void* __restrict__ Asrc, const unsigned short* __restrict__ Wt,
    const float* __restrict__ bias, const float* __restrict__ rowscale,
    void* __restrict__ Cout, int N, int K, int Ncols)
{
    constexpr int NF = BN / 32;
    __shared__ __align__(16) unsigned short As[2][128 * 64];
    __shared__ __align__(16) unsigned short Bs[2][BN * 64];

    const unsigned short* Ab = (const unsigned short*)Asrc;
    const float* Af = (const float*)Asrc;

    int bx, by;
    if constexpr (NYB == 2) {
        const int nXB = (N + 127) >> 7;
        int d = blockIdx.x;
        int xcd = d & 7, slot = d >> 3;
        by = slot & 1;
        bx = xcd + 8 * (slot >> 1);
        if (bx >= nXB) return;
    } else {
        bx = blockIdx.x; by = 0;
    }

    const int tid = threadIdx.x;
    const int wid = tid >> 6;
    const int lane = tid & 63;
    const int wr = wid >> 1;
    const int wc = wid & 1;
    const int rowBase = bx * 128;
    const int colBase = by * BN;

    f32x4 acc[4][NF];
    #pragma unroll
    for (int m = 0; m < 4; ++m)
        #pragma unroll
        for (int n = 0; n < NF; ++n)
            acc[m][n] = (f32x4)0.0f;

    const int sslot = (lane & 7) ^ (lane >> 3);   // pre-swizzled source slot (m173)

    float4 areg[4][2];

    auto stageA_g = [&](int buf, int k0) {
        #pragma unroll
        for (int it = 0; it < 4; ++it) {
            int ch = wid * 4 + it;
            int r = ch * 8 + (lane >> 3);
            int grow = rowBase + r; if (grow >= N) grow = N - 1;
            gload_lds16(Ab + (size_t)grow * K + k0 + sslot * 8, (void*)&As[buf][ch * 512]);
        }
    };
    auto issueA = [&](int k0) {
        #pragma unroll
        for (int it = 0; it < 4; ++it) {
            int ch = wid * 4 + it;
            int r = ch * 8 + (lane >> 3);
            int grow = rowBase + r; if (grow >= N) grow = N - 1;
            const float* src = Af + (size_t)grow * K + k0 + sslot * 8;
            areg[it][0] = *(const float4*)src;
            areg[it][1] = *(const float4*)(src + 4);
        }
    };
    auto writeA = [&](int buf) {
        #pragma unroll
        for (int it = 0; it < 4; ++it) {
            int ch = wid * 4 + it;
            short8 w;
            w[0] = (short)f2bf(areg[it][0].x); w[1] = (short)f2bf(areg[it][0].y);
            w[2] = (short)f2bf(areg[it][0].z); w[3] = (short)f2bf(areg[it][0].w);
            w[4] = (short)f2bf(areg[it][1].x); w[5] = (short)f2bf(areg[it][1].y);
            w[6] = (short)f2bf(areg[it][1].z); w[7] = (short)f2bf(areg[it][1].w);
            *(short8*)&As[buf][ch * 512 + lane * 8] = w;
        }
    };
    auto stageB = [&](int buf, int k0) {
        #pragma unroll
        for (int it = 0; it < NF; ++it) {
            int ch = wid * NF + it;
            int c = ch * 8 + (lane >> 3);
            gload_lds16(Wt + (size_t)(colBase + c) * K + k0 + sslot * 8, (void*)&Bs[buf][ch * 512]);
        }
    };

    const int nt = K >> 6;
    if constexpr (ASRC == 0) {
        stageA_g(0, 0);
        stageB(0, 0);
    } else {
        issueA(0);
        stageB(0, 0);
        writeA(0);
    }
    __syncthreads();

    int cur = 0;
    for (int t = 0; t < nt; ++t) {
        if (t + 1 < nt) {
            if constexpr (ASRC == 0) stageA_g(cur ^ 1, (t + 1) * 64);
            else issueA((t + 1) * 64);
            stageB(cur ^ 1, (t + 1) * 64);
        }
        #pragma unroll
        for (int ks = 0; ks < 2; ++ks) {
            short8 af[4];
            #pragma unroll
            for (int m = 0; m < 4; ++m) {
                int R = wr * 64 + m * 16 + (lane & 15);
                int p = (ks * 4 + (lane >> 4)) ^ (R & 7);
                af[m] = *(const short8*)(&As[cur][R * 64 + p * 8]);
            }
            #pragma unroll
            for (int n = 0; n < NF; ++n) {
                int Cc = wc * (BN / 2) + n * 16 + (lane & 15);
                int p = (ks * 4 + (lane >> 4)) ^ (Cc & 7);
                short8 bf = *(const short8*)(&Bs[cur][Cc * 64 + p * 8]);
                #pragma unroll
                for (int m = 0; m < 4; ++m)
                    acc[m][n] = __builtin_amdgcn_mfma_f32_16x16x32_bf16(af[m], bf, acc[m][n], 0, 0, 0);
            }
        }
        if (t + 1 < nt) {
            if constexpr (ASRC == 1) writeA(cur ^ 1);
            __syncthreads();
        }
        cur ^= 1;
    }

    float bv[NF];
    int colv[NF];
    #pragma unroll
    for (int n = 0; n < NF; ++n) {
        colv[n] = colBase + wc * (BN / 2) + n * 16 + (lane & 15);
        bv[n] = bias[colv[n]];
    }
    #pragma unroll
    for (int m = 0; m < 4; ++m) {
        #pragma unroll
        for (int q = 0; q < 4; ++q) {
            int row = rowBase + wr * 64 + m * 16 + (lane >> 4) * 4 + q;
            if (row >= N) continue;
            if (MODE == 0) {
                float sc = rowscale[row];
                unsigned short* Cb = (unsigned short*)Cout;
                #pragma unroll
                for (int n = 0; n < NF; ++n)
                    Cb[(size_t)row * Ncols + colv[n]] = f2bf((acc[m][n][q] + bv[n]) * sc);
            } else {
                float* Cf = (float*)Cout;
                #pragma unroll
                for (int n = 0; n < NF; ++n)
                    Cf[(size_t)row * Ncols + colv[n]] = acc[m][n][q] + bv[n];
            }
        }
    }
}

// ---------------- gather aggregate (full 512B rows, 8-deep ILP) ----------------
__global__ __launch_bounds__(256) void gather_agg_k(
    const int* __restrict__ rowstart, const int* __restrict__ csr,
    const float* __restrict__ dinv, const unsigned short* __restrict__ hp,
    unsigned short* __restrict__ out, int N)
{
    int c = __builtin_amdgcn_readfirstlane(blockIdx.x * 4 + (threadIdx.x >> 6));
    if (c >= N) return;
    int lane = threadIdx.x & 63;
    const ushort4* base = (const ushort4*)hp;
    int beg = rowstart[c], end = rowstart[c + 1];

    ushort4 sv = base[(size_t)c * 64 + lane];    // self loop
    float a0 = bf2f(sv.x), a1 = bf2f(sv.y), a2 = bf2f(sv.z), a3 = bf2f(sv.w);

    int e = beg;
    for (; e + 8 <= end; e += 8) {
        ushort4 v0 = base[(size_t)csr[e + 0] * 64 + lane];
        ushort4 v1 = base[(size_t)csr[e + 1] * 64 + lane];
        ushort4 v2 = base[(size_t)csr[e + 2] * 64 + lane];
        ushort4 v3 = base[(size_t)csr[e + 3] * 64 + lane];
        ushort4 v4 = base[(size_t)csr[e + 4] * 64 + lane];
        ushort4 v5 = base[(size_t)csr[e + 5] * 64 + lane];
        ushort4 v6 = base[(size_t)csr[e + 6] * 64 + lane];
        ushort4 v7 = base[(size_t)csr[e + 7] * 64 + lane];
        a0 += bf2f(v0.x) + bf2f(v1.x) + bf2f(v2.x) + bf2f(v3.x)
            + bf2f(v4.x) + bf2f(v5.x) + bf2f(v6.x) + bf2f(v7.x);
        a1 += bf2f(v0.y) + bf2f(v1.y) + bf2f(v2.y) + bf2f(v3.y)
            + bf2f(v4.y) + bf2f(v5.y) + bf2f(v6.y) + bf2f(v7.y);
        a2 += bf2f(v0.z) + bf2f(v1.z) + bf2f(v2.z) + bf2f(v3.z)
            + bf2f(v4.z) + bf2f(v5.z) + bf2f(v6.z) + bf2f(v7.z);
        a3 += bf2f(v0.w) + bf2f(v1.w) + bf2f(v2.w) + bf2f(v3.w)
            + bf2f(v4.w) + bf2f(v5.w) + bf2f(v6.w) + bf2f(v7.w);
    }
    for (; e + 4 <= end; e += 4) {
        ushort4 v0 = base[(size_t)csr[e + 0] * 64 + lane];
        ushort4 v1 = base[(size_t)csr[e + 1] * 64 + lane];
        ushort4 v2 = base[(size_t)csr[e + 2] * 64 + lane];
        ushort4 v3 = base[(size_t)csr[e + 3] * 64 + lane];
        a0 += bf2f(v0.x) + bf2f(v1.x) + bf2f(v2.x) + bf2f(v3.x);
        a1 += bf2f(v0.y) + bf2f(v1.y) + bf2f(v2.y) + bf2f(v3.y);
        a2 += bf2f(v0.z) + bf2f(v1.z) + bf2f(v2.z) + bf2f(v3.z);
        a3 += bf2f(v0.w) + bf2f(v1.w) + bf2f(v2.w) + bf2f(v3.w);
    }
    for (; e < end; ++e) {
        ushort4 v0 = base[(size_t)csr[e] * 64 + lane];
        a0 += bf2f(v0.x); a1 += bf2f(v0.y); a2 += bf2f(v0.z); a3 += bf2f(v0.w);
    }

    float sc = dinv[c];
    ushort4 o;
    o.x = f2bf(fmaxf(sc * a0, 0.f));
    o.y = f2bf(fmaxf(sc * a1, 0.f));
    o.z = f2bf(fmaxf(sc * a2, 0.f));
    o.w = f2bf(fmaxf(sc * a3, 0.f));
    ((ushort4*)out)[(size_t)c * 64 + lane] = o;
}

extern "C" void kernel_launch(void* const* d_in, const int* in_sizes, int n_in,
                              void* d_out, int out_size, void* d_ws, size_t ws_size,
                              hipStream_t stream) {
    const float* x  = (const float*)d_in[0];
    const int*  ei  = (const int*)d_in[1];
    const float* W1 = (const float*)d_in[2];
    const float* b1 = (const float*)d_in[3];
    const float* W2 = (const float*)d_in[4];
    const float* b2 = (const float*)d_in[5];
    const float* Wh = (const float*)d_in[6];
    const float* bh = (const float*)d_in[7];
    float* out = (float*)d_out;

    const int N = in_sizes[0] / 256;       // 50000
    const int E = in_sizes[1] / 2;         // 400000
    const int H = 256;
    const int C = 64;
    const int* rows = ei;
    const int* cols = ei + E;

    char* ws = (char*)d_ws;
    size_t off = 0;
    auto alloc = [&](size_t bytes) {
        void* p = ws + off;
        off = (off + bytes + 255) & ~(size_t)255;
        return p;
    };
    float* deg8     = (float*)alloc((size_t)8 * N * 4);  // contiguous with indeg8 for zeroing
    int*   indeg8   = (int*)alloc((size_t)8 * N * 4);
    int*   cursor8  = (int*)alloc((size_t)8 * N * 4);
    int*   rowstart = (int*)alloc((size_t)(N + 1) * 4);
    int*   bsums    = (int*)alloc(512 * 4);
    float* dinv     = (float*)alloc((size_t)N * 4);
    int*   csr      = (int*)alloc((size_t)E * 4);
    unsigned short* bufH = (unsigned short*)alloc((size_t)N * H * 2);
    unsigned short* bufA = (unsigned short*)alloc((size_t)N * H * 2);
    unsigned short* Wt1  = (unsigned short*)alloc((size_t)H * H * 2);
    unsigned short* Wt2  = (unsigned short*)alloc((size_t)H * H * 2);
    unsigned short* Wht  = (unsigned short*)alloc((size_t)C * H * 2);

    const int nbk = cdiv(N, 128);          // 391 scan blocks

    // ---- weights + zero replicated counters (deg8+indeg8 = 16N floats worth) ----
    const int nz4 = 4 * N;                 // (8N + 8N) * 4B / 16B
    prep_weights_zero_k<<<cdiv(nz4, 256), 256, 0, stream>>>(
        W1, W2, Wh, Wt1, Wt2, Wht, (float4*)deg8, nz4);
    count_both_k<<<cdiv(E, 256), 256, 0, stream>>>(rows, cols, deg8, indeg8, E, N);
    scan_block_k<<<nbk, 256, 0, stream>>>(indeg8, rowstart, cursor8, bsums, N);
    scan_add_dinv_k<<<cdiv(N, 256), 256, 0, stream>>>(
        rowstart, cursor8, bsums, nbk, deg8, dinv, N, E);
    fill_csr_k<<<cdiv(E, 256), 256, 0, stream>>>(rows, cols, cursor8, csr, E, N);

    const int nXB = cdiv(N, 128);          // 391
    dim3 g1(16 * cdiv(nXB, 8));            // XCD-paired decode in-kernel
    dim3 gh(nXB);

    // ---- layer 1 (fp32 x read directly; conversion fused into staging) ----
    gemm_mfma_k<128, 0, 1, 2><<<g1, 256, 0, stream>>>(x, Wt1, b1, dinv, bufH, N, H, H);
    gather_agg_k<<<cdiv(N, 4), 256, 0, stream>>>(rowstart, csr, dinv, bufH, bufA, N);

    // ---- layer 2 ----
    gemm_mfma_k<128, 0, 0, 2><<<g1, 256, 0, stream>>>(bufA, Wt2, b2, dinv, bufH, N, H, H);
    gather_agg_k<<<cdiv(N, 4), 256, 0, stream>>>(rowstart, csr, dinv, bufH, bufA, N);

    // ---- head ----
    gemm_mfma_k<64, 1, 0, 1><<<gh, 256, 0, stream>>>(bufA, Wht, bh, nullptr, out, N, H, C);
}

// Round 11
// 196.468 us; speedup vs baseline: 1.0147x; 1.0147x over previous
//
#include <hip/hip_runtime.h>
#include <hip/hip_bf16.h>

typedef __attribute__((ext_vector_type(8))) short short8;
typedef __attribute__((ext_vector_type(4))) float f32x4;

static inline int cdiv(int a, int b) { return (a + b - 1) / b; }

__device__ inline float bf2f(unsigned short u) {
    union { unsigned int u; float f; } a; a.u = ((unsigned int)u) << 16; return a.f;
}
__device__ inline unsigned short f2bf(float f) {
    union { float f; unsigned int u; } a; a.f = f;
    unsigned int r = a.u + 0x7fff + ((a.u >> 16) & 1);
    return (unsigned short)(r >> 16);
}
__device__ inline void gload_lds16(const void* g, void* l) {
    __builtin_amdgcn_global_load_lds(
        (const __attribute__((address_space(1))) unsigned int*)g,
        (__attribute__((address_space(3))) unsigned int*)l, 16, 0, 0);
}

// ---------------- preprocessing (unchanged from r10) ----------------
__global__ __launch_bounds__(256) void count_both_k(
    const int* __restrict__ rows, const int* __restrict__ cols,
    float* deg8, int* indeg8, int E, int N)
{
    int rep = blockIdx.x & 7;
    int e = blockIdx.x * 256 + threadIdx.x;
    if (e < E) {
        atomicAdd(&deg8[rep * N + rows[e]], 1.0f);
        atomicAdd(&indeg8[rep * N + cols[e]], 1);
    }
}

__global__ __launch_bounds__(256) void scan_block_k(
    const int* __restrict__ indeg8, int* __restrict__ rowstart,
    int* __restrict__ cursor8, int* __restrict__ bsums, int N)
{
    __shared__ int smem[256];
    int b = blockIdx.x, t = threadIdx.x;
    int node = b * 128 + (t >> 1);
    int half = t & 1;
    int v[4];
    int s = 0;
    #pragma unroll
    for (int j = 0; j < 4; ++j) {
        int rep = half * 4 + j;
        v[j] = (node < N) ? indeg8[rep * N + node] : 0;
        s += v[j];
    }
    smem[t] = s;
    __syncthreads();
    for (int off = 1; off < 256; off <<= 1) {
        int x = smem[t];
        int y = (t >= off) ? smem[t - off] : 0;
        __syncthreads();
        smem[t] = x + y;
        __syncthreads();
    }
    int excl = smem[t] - s;
    if (node < N) {
        int p = excl;
        #pragma unroll
        for (int j = 0; j < 4; ++j) {
            int rep = half * 4 + j;
            cursor8[rep * N + node] = p;
            p += v[j];
        }
        if (half == 0) rowstart[node] = excl;
    }
    if (t == 255) bsums[b] = smem[255];
}

__global__ __launch_bounds__(256) void scan_add_dinv_k(
    int* rowstart, int* cursor8, const int* __restrict__ bsums, int nbk,
    const float* __restrict__ deg8, float* __restrict__ dinv, int N, int E)
{
    __shared__ int sb[512];
    int t = threadIdx.x;
    sb[t]       = (t < nbk) ? bsums[t] : 0;
    sb[t + 256] = (t + 256 < nbk) ? bsums[t + 256] : 0;
    __syncthreads();
    for (int off = 1; off < 512; off <<= 1) {
        int x0 = sb[t]       + ((t >= off) ? sb[t - off] : 0);
        int x1 = sb[t + 256] + ((t + 256 >= off) ? sb[t + 256 - off] : 0);
        __syncthreads();
        sb[t] = x0; sb[t + 256] = x1;
        __syncthreads();
    }
    int i = blockIdx.x * 256 + t;
    if (i < N) {
        int blk = i >> 7;
        int off = (blk == 0) ? 0 : sb[blk - 1];
        rowstart[i] += off;
        float d = 1.0f;
        #pragma unroll
        for (int rep = 0; rep < 8; ++rep) {
            cursor8[rep * N + i] += off;
            d += deg8[rep * N + i];
        }
        dinv[i] = rsqrtf(d);
    }
    if (blockIdx.x == 0 && t == 0) rowstart[N] = E;
}

__global__ __launch_bounds__(256) void fill_csr_k(
    const int* __restrict__ rows, const int* __restrict__ cols,
    int* cursor8, int* __restrict__ csr, int E, int N)
{
    int rep = blockIdx.x & 7;
    int e = blockIdx.x * 256 + threadIdx.x;
    if (e < E) {
        int pos = atomicAdd(&cursor8[rep * N + cols[e]], 1);
        csr[pos] = rows[e];
    }
}

__global__ __launch_bounds__(256) void prep_weights_zero_k(
    const float* __restrict__ W1, const float* __restrict__ W2, const float* __restrict__ Wh,
    unsigned short* __restrict__ Wt1, unsigned short* __restrict__ Wt2, unsigned short* __restrict__ Wht,
    float4* __restrict__ zp, int nz4)
{
    int idx = blockIdx.x * 256 + threadIdx.x;
    if (idx < nz4) zp[idx] = make_float4(0.f, 0.f, 0.f, 0.f);
    if (idx < 65536) {
        int k = idx >> 8, m = idx & 255;
        Wt1[m * 256 + k] = f2bf(W1[idx]);
    } else if (idx < 131072) {
        int i = idx - 65536;
        int k = i >> 8, m = i & 255;
        Wt2[m * 256 + k] = f2bf(W2[i]);
    } else if (idx < 147456) {
        int i = idx - 131072;
        int k = i >> 6, m = i & 63;    // Wh is 256 x 64
        Wht[m * 256 + k] = f2bf(Wh[i]);
    }
}

// ---------------- MFMA GEMM, 2-phase double-buffered, parametric tile ----------------
// BM=256: 8 waves (512 thr), LDS 128KB, wave grid 2x4, wave tile 128x64.
// BM=128: 4 waves (256 thr), wave grid 2x2 (BN=128) wave tile 64x64; BN=64 -> 64x32.
// ASRC 0: A bf16 via global_load_lds; ASRC 1: A fp32 via reg-stage + cvt (T14).
template<int BM, int BN, int MODE, int ASRC>
__global__ __launch_bounds__(BM == 256 ? 512 : 256) void gemm_mfma_k(
    const void* __restrict__ Asrc, const unsigned short* __restrict__ Wt,
    const float* __restrict__ bias, const float* __restrict__ rowscale,
    void* __restrict__ Cout, int N, int K, int Ncols)
{
    constexpr int NW  = (BM == 256) ? 8 : 4;   // waves
    constexpr int WC  = NW / 2;                // wave cols (2 or 4)
    constexpr int MR  = BM / 32;               // m-frags per wave (4 or 8)
    constexpr int NF  = BN / (WC * 16);        // n-frags per wave
    constexpr int BIT = (BN / 8) / NW;         // B-chunks per wave

    __shared__ __align__(16) unsigned short As[2][BM * 64];
    __shared__ __align__(16) unsigned short Bs[2][BN * 64];

    const unsigned short* Ab = (const unsigned short*)Asrc;
    const float* Af = (const float*)Asrc;

    const int tid = threadIdx.x;
    const int wid = tid >> 6;
    const int lane = tid & 63;
    const int wr = wid / WC;
    const int wc = wid % WC;
    const int rowBase = blockIdx.x * BM;
    const int colBase = 0;                      // BN spans all output cols

    f32x4 acc[MR][NF];
    #pragma unroll
    for (int m = 0; m < MR; ++m)
        #pragma unroll
        for (int n = 0; n < NF; ++n)
            acc[m][n] = (f32x4)0.0f;

    const int sslot = (lane & 7) ^ (lane >> 3);   // pre-swizzled source slot (m173)

    float4 areg[4][2];

    auto stageA_g = [&](int buf, int k0) {
        #pragma unroll
        for (int it = 0; it < 4; ++it) {
            int ch = wid * 4 + it;
            int r = ch * 8 + (lane >> 3);
            int grow = rowBase + r; if (grow >= N) grow = N - 1;
            gload_lds16(Ab + (size_t)grow * K + k0 + sslot * 8, (void*)&As[buf][ch * 512]);
        }
    };
    auto issueA = [&](int k0) {
        #pragma unroll
        for (int it = 0; it < 4; ++it) {
            int ch = wid * 4 + it;
            int r = ch * 8 + (lane >> 3);
            int grow = rowBase + r; if (grow >= N) grow = N - 1;
            const float* src = Af + (size_t)grow * K + k0 + sslot * 8;
            areg[it][0] = *(const float4*)src;
            areg[it][1] = *(const float4*)(src + 4);
        }
    };
    auto writeA = [&](int buf) {
        #pragma unroll
        for (int it = 0; it < 4; ++it) {
            int ch = wid * 4 + it;
            short8 w;
            w[0] = (short)f2bf(areg[it][0].x); w[1] = (short)f2bf(areg[it][0].y);
            w[2] = (short)f2bf(areg[it][0].z); w[3] = (short)f2bf(areg[it][0].w);
            w[4] = (short)f2bf(areg[it][1].x); w[5] = (short)f2bf(areg[it][1].y);
            w[6] = (short)f2bf(areg[it][1].z); w[7] = (short)f2bf(areg[it][1].w);
            *(short8*)&As[buf][ch * 512 + lane * 8] = w;
        }
    };
    auto stageB = [&](int buf, int k0) {
        #pragma unroll
        for (int it = 0; it < BIT; ++it) {
            int ch = wid * BIT + it;
            int c = ch * 8 + (lane >> 3);
            gload_lds16(Wt + (size_t)(colBase + c) * K + k0 + sslot * 8, (void*)&Bs[buf][ch * 512]);
        }
    };

    const int nt = K >> 6;       // 4 for K=256
    if constexpr (ASRC == 0) {
        stageA_g(0, 0);
        stageB(0, 0);
    } else {
        issueA(0);
        stageB(0, 0);
        writeA(0);
    }
    __syncthreads();

    int cur = 0;
    for (int t = 0; t < nt; ++t) {
        if (t + 1 < nt) {
            if constexpr (ASRC == 0) stageA_g(cur ^ 1, (t + 1) * 64);
            else issueA((t + 1) * 64);
            stageB(cur ^ 1, (t + 1) * 64);
        }
        #pragma unroll
        for (int ks = 0; ks < 2; ++ks) {
            short8 af[MR];
            #pragma unroll
            for (int m = 0; m < MR; ++m) {
                int R = wr * (MR * 16) + m * 16 + (lane & 15);
                int p = (ks * 4 + (lane >> 4)) ^ (R & 7);
                af[m] = *(const short8*)(&As[cur][R * 64 + p * 8]);
            }
            #pragma unroll
            for (int n = 0; n < NF; ++n) {
                int Cc = wc * (NF * 16) + n * 16 + (lane & 15);
                int p = (ks * 4 + (lane >> 4)) ^ (Cc & 7);
                short8 bf = *(const short8*)(&Bs[cur][Cc * 64 + p * 8]);
                #pragma unroll
                for (int m = 0; m < MR; ++m)
                    acc[m][n] = __builtin_amdgcn_mfma_f32_16x16x32_bf16(af[m], bf, acc[m][n], 0, 0, 0);
            }
        }
        if (t + 1 < nt) {
            if constexpr (ASRC == 1) writeA(cur ^ 1);
            __syncthreads();
        }
        cur ^= 1;
    }

    // epilogue: C/D layout col=lane&15, row=(lane>>4)*4+q  [m89-verified]
    float bv[NF];
    int colv[NF];
    #pragma unroll
    for (int n = 0; n < NF; ++n) {
        colv[n] = colBase + wc * (NF * 16) + n * 16 + (lane & 15);
        bv[n] = bias[colv[n]];
    }
    #pragma unroll
    for (int m = 0; m < MR; ++m) {
        #pragma unroll
        for (int q = 0; q < 4; ++q) {
            int row = rowBase + wr * (MR * 16) + m * 16 + (lane >> 4) * 4 + q;
            if (row >= N) continue;
            if (MODE == 0) {
                float sc = rowscale[row];
                unsigned short* Cb = (unsigned short*)Cout;
                #pragma unroll
                for (int n = 0; n < NF; ++n)
                    Cb[(size_t)row * Ncols + colv[n]] = f2bf((acc[m][n][q] + bv[n]) * sc);
            } else {
                float* Cf = (float*)Cout;
                #pragma unroll
                for (int n = 0; n < NF; ++n)
                    Cf[(size_t)row * Ncols + colv[n]] = acc[m][n][q] + bv[n];
            }
        }
    }
}

// ---------------- gather aggregate (full 512B rows, 8-deep ILP) ----------------
__global__ __launch_bounds__(256) void gather_agg_k(
    const int* __restrict__ rowstart, const int* __restrict__ csr,
    const float* __restrict__ dinv, const unsigned short* __restrict__ hp,
    unsigned short* __restrict__ out, int N)
{
    int c = __builtin_amdgcn_readfirstlane(blockIdx.x * 4 + (threadIdx.x >> 6));
    if (c >= N) return;
    int lane = threadIdx.x & 63;
    const ushort4* base = (const ushort4*)hp;
    int beg = rowstart[c], end = rowstart[c + 1];

    ushort4 sv = base[(size_t)c * 64 + lane];    // self loop
    float a0 = bf2f(sv.x), a1 = bf2f(sv.y), a2 = bf2f(sv.z), a3 = bf2f(sv.w);

    int e = beg;
    for (; e + 8 <= end; e += 8) {
        ushort4 v0 = base[(size_t)csr[e + 0] * 64 + lane];
        ushort4 v1 = base[(size_t)csr[e + 1] * 64 + lane];
        ushort4 v2 = base[(size_t)csr[e + 2] * 64 + lane];
        ushort4 v3 = base[(size_t)csr[e + 3] * 64 + lane];
        ushort4 v4 = base[(size_t)csr[e + 4] * 64 + lane];
        ushort4 v5 = base[(size_t)csr[e + 5] * 64 + lane];
        ushort4 v6 = base[(size_t)csr[e + 6] * 64 + lane];
        ushort4 v7 = base[(size_t)csr[e + 7] * 64 + lane];
        a0 += bf2f(v0.x) + bf2f(v1.x) + bf2f(v2.x) + bf2f(v3.x)
            + bf2f(v4.x) + bf2f(v5.x) + bf2f(v6.x) + bf2f(v7.x);
        a1 += bf2f(v0.y) + bf2f(v1.y) + bf2f(v2.y) + bf2f(v3.y)
            + bf2f(v4.y) + bf2f(v5.y) + bf2f(v6.y) + bf2f(v7.y);
        a2 += bf2f(v0.z) + bf2f(v1.z) + bf2f(v2.z) + bf2f(v3.z)
            + bf2f(v4.z) + bf2f(v5.z) + bf2f(v6.z) + bf2f(v7.z);
        a3 += bf2f(v0.w) + bf2f(v1.w) + bf2f(v2.w) + bf2f(v3.w)
            + bf2f(v4.w) + bf2f(v5.w) + bf2f(v6.w) + bf2f(v7.w);
    }
    for (; e + 4 <= end; e += 4) {
        ushort4 v0 = base[(size_t)csr[e + 0] * 64 + lane];
        ushort4 v1 = base[(size_t)csr[e + 1] * 64 + lane];
        ushort4 v2 = base[(size_t)csr[e + 2] * 64 + lane];
        ushort4 v3 = base[(size_t)csr[e + 3] * 64 + lane];
        a0 += bf2f(v0.x) + bf2f(v1.x) + bf2f(v2.x) + bf2f(v3.x);
        a1 += bf2f(v0.y) + bf2f(v1.y) + bf2f(v2.y) + bf2f(v3.y);
        a2 += bf2f(v0.z) + bf2f(v1.z) + bf2f(v2.z) + bf2f(v3.z);
        a3 += bf2f(v0.w) + bf2f(v1.w) + bf2f(v2.w) + bf2f(v3.w);
    }
    for (; e < end; ++e) {
        ushort4 v0 = base[(size_t)csr[e] * 64 + lane];
        a0 += bf2f(v0.x); a1 += bf2f(v0.y); a2 += bf2f(v0.z); a3 += bf2f(v0.w);
    }

    float sc = dinv[c];
    ushort4 o;
    o.x = f2bf(fmaxf(sc * a0, 0.f));
    o.y = f2bf(fmaxf(sc * a1, 0.f));
    o.z = f2bf(fmaxf(sc * a2, 0.f));
    o.w = f2bf(fmaxf(sc * a3, 0.f));
    ((ushort4*)out)[(size_t)c * 64 + lane] = o;
}

extern "C" void kernel_launch(void* const* d_in, const int* in_sizes, int n_in,
                              void* d_out, int out_size, void* d_ws, size_t ws_size,
                              hipStream_t stream) {
    const float* x  = (const float*)d_in[0];
    const int*  ei  = (const int*)d_in[1];
    const float* W1 = (const float*)d_in[2];
    const float* b1 = (const float*)d_in[3];
    const float* W2 = (const float*)d_in[4];
    const float* b2 = (const float*)d_in[5];
    const float* Wh = (const float*)d_in[6];
    const float* bh = (const float*)d_in[7];
    float* out = (float*)d_out;

    const int N = in_sizes[0] / 256;       // 50000
    const int E = in_sizes[1] / 2;         // 400000
    const int H = 256;
    const int C = 64;
    const int* rows = ei;
    const int* cols = ei + E;

    char* ws = (char*)d_ws;
    size_t off = 0;
    auto alloc = [&](size_t bytes) {
        void* p = ws + off;
        off = (off + bytes + 255) & ~(size_t)255;
        return p;
    };
    float* deg8     = (float*)alloc((size_t)8 * N * 4);  // contiguous with indeg8 for zeroing
    int*   indeg8   = (int*)alloc((size_t)8 * N * 4);
    int*   cursor8  = (int*)alloc((size_t)8 * N * 4);
    int*   rowstart = (int*)alloc((size_t)(N + 1) * 4);
    int*   bsums    = (int*)alloc(512 * 4);
    float* dinv     = (float*)alloc((size_t)N * 4);
    int*   csr      = (int*)alloc((size_t)E * 4);
    unsigned short* bufH = (unsigned short*)alloc((size_t)N * H * 2);
    unsigned short* bufA = (unsigned short*)alloc((size_t)N * H * 2);
    unsigned short* Wt1  = (unsigned short*)alloc((size_t)H * H * 2);
    unsigned short* Wt2  = (unsigned short*)alloc((size_t)H * H * 2);
    unsigned short* Wht  = (unsigned short*)alloc((size_t)C * H * 2);

    const int nbk = cdiv(N, 128);          // 391 scan blocks

    // ---- weights + zero replicated counters ----
    const int nz4 = 4 * N;
    prep_weights_zero_k<<<cdiv(nz4, 256), 256, 0, stream>>>(
        W1, W2, Wh, Wt1, Wt2, Wht, (float4*)deg8, nz4);
    count_both_k<<<cdiv(E, 256), 256, 0, stream>>>(rows, cols, deg8, indeg8, E, N);
    scan_block_k<<<nbk, 256, 0, stream>>>(indeg8, rowstart, cursor8, bsums, N);
    scan_add_dinv_k<<<cdiv(N, 256), 256, 0, stream>>>(
        rowstart, cursor8, bsums, nbk, deg8, dinv, N, E);
    fill_csr_k<<<cdiv(E, 256), 256, 0, stream>>>(rows, cols, cursor8, csr, E, N);

    dim3 g1(cdiv(N, 256));                 // 196 blocks, 512 threads (256^2 tile)
    dim3 gh(cdiv(N, 128));                 // 391 blocks, 256 threads (head)

    // ---- layer 1 (fp32 x read directly; conversion fused into staging) ----
    gemm_mfma_k<256, 256, 0, 1><<<g1, 512, 0, stream>>>(x, Wt1, b1, dinv, bufH, N, H, H);
    gather_agg_k<<<cdiv(N, 4), 256, 0, stream>>>(rowstart, csr, dinv, bufH, bufA, N);

    // ---- layer 2 ----
    gemm_mfma_k<256, 256, 0, 0><<<g1, 512, 0, stream>>>(bufA, Wt2, b2, dinv, bufH, N, H, H);
    gather_agg_k<<<cdiv(N, 4), 256, 0, stream>>>(rowstart, csr, dinv, bufH, bufA, N);

    // ---- head ----
    gemm_mfma_k<128, 64, 1, 0><<<gh, 256, 0, stream>>>(bufA, Wht, bh, nullptr, out, N, H, C);
}